// Round 1
// baseline (5888.899 us; speedup 1.0000x reference)
//
#include <hip/hip_runtime.h>
#include <math.h>

#define T_STEPS 256
#define BATCH   128
#define IDIM    1024
#define HDIM    1024
#define NCLS    16

// ================= Phase 1: xw[t*B+b][h] = x @ W_ih^T + (b_ih + b_hh) ==========
// M=32768, N=1024, K=1024. A = x [M,K] row-major, Bw = W_ih [N,K] row-major
// (both k-contiguous -> "B^T input" GEMM). 128x128 tile, BK=16, 8x8/thread.
__global__ __launch_bounds__(256) void gemm_xw_kernel(
    const float* __restrict__ A, const float* __restrict__ Bw,
    const float* __restrict__ bih, const float* __restrict__ bhh,
    float* __restrict__ C)
{
    __shared__ float As[16][132];   // +4 pad: 2-way max on transposed writes
    __shared__ float Bs[16][132];
    const int tid = threadIdx.x;
    const int bm0 = blockIdx.y * 128;
    const int bn0 = blockIdx.x * 128;
    const int tx = tid & 15, ty = tid >> 4;

    float acc[8][8];
#pragma unroll
    for (int i = 0; i < 8; ++i)
#pragma unroll
        for (int j = 0; j < 8; ++j) acc[i][j] = 0.f;

    for (int k0 = 0; k0 < IDIM; k0 += 16) {
#pragma unroll
        for (int l = 0; l < 2; ++l) {
            const int idx = tid + l * 256;          // 0..511
            const int row = idx >> 2, kq = (idx & 3) * 4;
            const float4 va = *reinterpret_cast<const float4*>(
                &A[(size_t)(bm0 + row) * IDIM + k0 + kq]);
            As[kq + 0][row] = va.x; As[kq + 1][row] = va.y;
            As[kq + 2][row] = va.z; As[kq + 3][row] = va.w;
            const float4 vb = *reinterpret_cast<const float4*>(
                &Bw[(size_t)(bn0 + row) * IDIM + k0 + kq]);
            Bs[kq + 0][row] = vb.x; Bs[kq + 1][row] = vb.y;
            Bs[kq + 2][row] = vb.z; Bs[kq + 3][row] = vb.w;
        }
        __syncthreads();
#pragma unroll
        for (int k = 0; k < 16; ++k) {
            // split-quad fragments: rows {4ty..+3, 64+4ty..+3}, cols {4tx..,64+4tx..}
            const float4 alo = *reinterpret_cast<const float4*>(&As[k][4 * ty]);
            const float4 ahi = *reinterpret_cast<const float4*>(&As[k][64 + 4 * ty]);
            const float4 blo = *reinterpret_cast<const float4*>(&Bs[k][4 * tx]);
            const float4 bhi = *reinterpret_cast<const float4*>(&Bs[k][64 + 4 * tx]);
            const float a[8] = {alo.x, alo.y, alo.z, alo.w, ahi.x, ahi.y, ahi.z, ahi.w};
            const float b[8] = {blo.x, blo.y, blo.z, blo.w, bhi.x, bhi.y, bhi.z, bhi.w};
#pragma unroll
            for (int i = 0; i < 8; ++i)
#pragma unroll
                for (int j = 0; j < 8; ++j)
                    acc[i][j] = fmaf(a[i], b[j], acc[i][j]);
        }
        __syncthreads();
    }

    const float4 bl0 = *reinterpret_cast<const float4*>(&bih[bn0 + 4 * tx]);
    const float4 bl1 = *reinterpret_cast<const float4*>(&bhh[bn0 + 4 * tx]);
    const float4 bh0 = *reinterpret_cast<const float4*>(&bih[bn0 + 64 + 4 * tx]);
    const float4 bh1 = *reinterpret_cast<const float4*>(&bhh[bn0 + 64 + 4 * tx]);
    const float4 biaslo = {bl0.x + bl1.x, bl0.y + bl1.y, bl0.z + bl1.z, bl0.w + bl1.w};
    const float4 biashi = {bh0.x + bh1.x, bh0.y + bh1.y, bh0.z + bh1.z, bh0.w + bh1.w};
#pragma unroll
    for (int i = 0; i < 8; ++i) {
        const int m = bm0 + 4 * ty + (i & 3) + (i >> 2) * 64;
        const float4 lo = {acc[i][0] + biaslo.x, acc[i][1] + biaslo.y,
                           acc[i][2] + biaslo.z, acc[i][3] + biaslo.w};
        const float4 hi = {acc[i][4] + biashi.x, acc[i][5] + biashi.y,
                           acc[i][6] + biashi.z, acc[i][7] + biashi.w};
        *reinterpret_cast<float4*>(&C[(size_t)m * HDIM + bn0 + 4 * tx]) = lo;
        *reinterpret_cast<float4*>(&C[(size_t)m * HDIM + bn0 + 64 + 4 * tx]) = hi;
    }
}

// ================= Phase 2: persistent cooperative recurrence ==================
// 256 blocks x 256 threads, 1 block/CU. Block (bg,hg): b-rows bg*16..+15,
// h-cols hg*32..+31. W_hh slice [32][1024] lives in LDS for all 256 steps
// (float4-column XOR swizzle -> 2-way max conflicts). k-split 16 across
// threads; per-thread register tile 4b x 8h. Per-b-group barrier (8 groups
// of 32 blocks; bg == blockIdx%8 -> one XCD per group under round-robin).
__global__ __launch_bounds__(256, 1) void rnn_scan_kernel(
    const float* __restrict__ xw, const float* __restrict__ Whh,
    float* __restrict__ hx0buf, float* __restrict__ hx1buf,
    unsigned* __restrict__ bar)
{
    __shared__ float4 Ws4[32 * 256];      // 128 KB, swizzled cols
    __shared__ float4 hs4[16 * 65];       // 16.25 KB, stride 65 f4 (pad)
    __shared__ float  red[4][16][36];     // 9 KB cross-wave reduce scratch
    const int tid = threadIdx.x;
    const int bg  = blockIdx.x & 7;       // XCD-affine b-group
    const int hg  = blockIdx.x >> 3;      // 0..31
    const int b0  = bg * 16;
    const int h0  = hg * 32;

    // ---- load persistent W tile (swizzled) ----
    for (int idx = tid; idx < 32 * 256; idx += 256) {
        const int r = idx >> 8, q = idx & 255;
        Ws4[r * 256 + (q ^ (((r >> 3) & 3) << 2))] =
            *reinterpret_cast<const float4*>(&Whh[(size_t)(h0 + r) * HDIM + q * 4]);
    }

    const int ks    = tid >> 4;           // 0..15 k-split index
    const int og    = tid & 15;
    const int bq    = og >> 2;            // rows b0 + bq*4 .. +3
    const int hgrp  = og & 3;             // cols h0 + hgrp*8 .. +7
    const int wv_sw = hgrp << 2;

    // epilogue indices are static per thread (2 consecutive-h outputs)
    const int out0 = tid * 2;
    const int ogo  = out0 >> 5;
    const int m0   = out0 & 31;           // even
    const int b_ep = b0 + (ogo >> 2) * 4 + (m0 >> 3);
    const int h_ep = h0 + (ogo & 3) * 8 + (m0 & 7);

    __syncthreads();                      // Ws ready

    for (int t = 0; t < T_STEPS; ++t) {
        const float* __restrict__ hcur = (t & 1) ? hx1buf : hx0buf;
        float*       __restrict__ hnxt = (t & 1) ? hx0buf : hx1buf;

        // prefetch the xw pair needed at the epilogue (hidden under compute)
        const float2 xv = *reinterpret_cast<const float2*>(
            &xw[((size_t)t * BATCH + b_ep) * HDIM + h_ep]);

        float acc[4][8];
#pragma unroll
        for (int i = 0; i < 4; ++i)
#pragma unroll
            for (int j = 0; j < 8; ++j) acc[i][j] = 0.f;

        // prefetch chunk 0 of hx (16 rows x 256 floats)
        float4 stg[4];
#pragma unroll
        for (int l = 0; l < 4; ++l) {
            const int idx = tid + l * 256;            // 0..1023 float4s
            const int row = idx >> 6, q = idx & 63;
            stg[l] = *reinterpret_cast<const float4*>(
                &hcur[(size_t)(b0 + row) * HDIM + q * 4]);
        }

        for (int c = 0; c < 4; ++c) {                 // 4 k-chunks of 256
#pragma unroll
            for (int l = 0; l < 4; ++l) {
                const int idx = tid + l * 256;
                hs4[(idx >> 6) * 65 + (idx & 63)] = stg[l];
            }
            __syncthreads();
            if (c < 3) {                              // prefetch next chunk
#pragma unroll
                for (int l = 0; l < 4; ++l) {
                    const int idx = tid + l * 256;
                    const int row = idx >> 6, q = idx & 63;
                    stg[l] = *reinterpret_cast<const float4*>(
                        &hcur[(size_t)(b0 + row) * HDIM + (c + 1) * 256 + q * 4]);
                }
            }
            const int cbase = c * 64;
#pragma unroll
            for (int kk = 0; kk < 4; ++kk) {
                const int qc = kk * 16 + ks;          // in-chunk float4 col
                float4 hv[4];
#pragma unroll
                for (int i = 0; i < 4; ++i) hv[i] = hs4[(bq * 4 + i) * 65 + qc];
#pragma unroll
                for (int j = 0; j < 8; ++j) {
                    const float4 wv = Ws4[(hgrp * 8 + j) * 256 + ((cbase + qc) ^ wv_sw)];
#pragma unroll
                    for (int i = 0; i < 4; ++i)
                        acc[i][j] = fmaf(hv[i].x, wv.x, fmaf(hv[i].y, wv.y,
                                    fmaf(hv[i].z, wv.z, fmaf(hv[i].w, wv.w, acc[i][j]))));
                }
            }
            __syncthreads();
        }

        // ---- k-split reduction: intra-wave over ks&3 via shuffles ----
#pragma unroll
        for (int i = 0; i < 4; ++i)
#pragma unroll
            for (int j = 0; j < 8; ++j) {
                float v = acc[i][j];
                v += __shfl_xor(v, 16, 64);
                v += __shfl_xor(v, 32, 64);
                acc[i][j] = v;
            }
        const int w = tid >> 6, lane = tid & 63;
        if ((lane >> 4) == 0) {
#pragma unroll
            for (int i = 0; i < 4; ++i)
#pragma unroll
                for (int j = 0; j < 8; ++j)
                    red[w][lane][i * 8 + j] = acc[i][j];
        }
        __syncthreads();

        const float y0 = red[0][ogo][m0]     + red[1][ogo][m0]
                       + red[2][ogo][m0]     + red[3][ogo][m0];
        const float y1 = red[0][ogo][m0 + 1] + red[1][ogo][m0 + 1]
                       + red[2][ogo][m0 + 1] + red[3][ogo][m0 + 1];
        float2 hnew;
        hnew.x = tanhf(xv.x + y0);
        hnew.y = tanhf(xv.y + y1);
        *reinterpret_cast<float2*>(&hnxt[(size_t)b_ep * HDIM + h_ep]) = hnew;

        if (t < T_STEPS - 1) {
            __syncthreads();   // drain all threads' hx stores (vmcnt before barrier)
            if (tid == 0) {
                __hip_atomic_fetch_add(&bar[bg], 1u, __ATOMIC_RELEASE,
                                       __HIP_MEMORY_SCOPE_AGENT);
                const unsigned target = 32u * (unsigned)(t + 1);
                while (__hip_atomic_load(&bar[bg], __ATOMIC_ACQUIRE,
                                         __HIP_MEMORY_SCOPE_AGENT) < target)
                    __builtin_amdgcn_s_sleep(1);
            }
            __syncthreads();
        }
    }
}

// ================= Phase 3: out = sigmoid(hx @ W_fc^T + b_fc) ==================
__global__ __launch_bounds__(64) void fc_kernel(
    const float* __restrict__ hx, const float* __restrict__ Wfc,
    const float* __restrict__ bfc, float* __restrict__ out)
{
    const int b = blockIdx.x >> 4, cls = blockIdx.x & 15, lane = threadIdx.x;
    float sum = 0.f;
#pragma unroll
    for (int qq = 0; qq < 4; ++qq) {
        const int f = (qq * 64 + lane) * 4;
        const float4 h4 = *reinterpret_cast<const float4*>(&hx[(size_t)b * HDIM + f]);
        const float4 w4 = *reinterpret_cast<const float4*>(&Wfc[(size_t)cls * HDIM + f]);
        sum = fmaf(h4.x, w4.x, fmaf(h4.y, w4.y, fmaf(h4.z, w4.z, fmaf(h4.w, w4.w, sum))));
    }
#pragma unroll
    for (int off = 32; off > 0; off >>= 1) sum += __shfl_xor(sum, off, 64);
    if (lane == 0) out[b * NCLS + cls] = 1.f / (1.f + expf(-(sum + bfc[cls])));
}

// ================================ launch ======================================
extern "C" void kernel_launch(void* const* d_in, const int* in_sizes, int n_in,
                              void* d_out, int out_size, void* d_ws, size_t ws_size,
                              hipStream_t stream) {
    const float* x   = (const float*)d_in[0];
    const float* Wih = (const float*)d_in[1];
    const float* Whh = (const float*)d_in[2];
    const float* bih = (const float*)d_in[3];
    const float* bhh = (const float*)d_in[4];
    const float* Wfc = (const float*)d_in[5];
    const float* bfc = (const float*)d_in[6];
    float* out = (float*)d_out;

    // workspace layout: xw (128 MB) | hxA (512 KB) | hxB (512 KB) | bar (32 B)
    float* xw  = (float*)d_ws;
    float* hxA = xw + (size_t)T_STEPS * BATCH * HDIM;
    float* hxB = hxA + BATCH * HDIM;
    unsigned* bar = (unsigned*)(hxB + BATCH * HDIM);

    hipMemsetAsync(hxA, 0, BATCH * HDIM * sizeof(float), stream);  // hx0 = 0
    hipMemsetAsync(bar, 0, 8 * sizeof(unsigned), stream);

    dim3 g1(HDIM / 128, (T_STEPS * BATCH) / 128);   // (8, 256)
    gemm_xw_kernel<<<g1, 256, 0, stream>>>(x, Wih, bih, bhh, xw);

    void* args[] = { (void*)&xw, (void*)&Whh, (void*)&hxA, (void*)&hxB, (void*)&bar };
    hipLaunchCooperativeKernel((const void*)rnn_scan_kernel, dim3(256), dim3(256),
                               args, 0, stream);

    fc_kernel<<<dim3(BATCH * NCLS), dim3(64), 0, stream>>>(hxA, Wfc, bfc, out);
}

// Round 2
// 3006.586 us; speedup vs baseline: 1.9587x; 1.9587x over previous
//
#include <hip/hip_runtime.h>
#include <math.h>

#define T_STEPS 256
#define BATCH   128
#define IDIM    1024
#define HDIM    1024
#define NCLS    16

using f32x4 = __attribute__((ext_vector_type(4))) float;
using f32x2 = __attribute__((ext_vector_type(2))) float;

// Device-coherent (MALL-level) accesses: correct regardless of XCD placement,
// and they never trigger cache-wide wbl2/inv (which was nuking xw/W L2 lines).
__device__ __forceinline__ f32x4 load_dev_x4(const float* p) {
    f32x4 r;
    asm volatile("global_load_dwordx4 %0, %1, off sc0 sc1"
                 : "=v"(r) : "v"(p) : "memory");
    return r;
}
__device__ __forceinline__ void store_dev_x2(float* p, f32x2 v) {
    asm volatile("global_store_dwordx2 %0, %1, off sc0 sc1"
                 :: "v"(p), "v"(v) : "memory");
}
__device__ __forceinline__ void store_dev_u32(unsigned* p, unsigned v) {
    asm volatile("global_store_dword %0, %1, off sc0 sc1"
                 :: "v"(p), "v"(v) : "memory");
}
__device__ __forceinline__ void wait_vm0() {
    asm volatile("s_waitcnt vmcnt(0)" ::: "memory");
    __builtin_amdgcn_sched_barrier(0);
}

// ================= Phase 1: xw[t*B+b][h] = x @ W_ih^T + (b_ih + b_hh) ==========
__global__ __launch_bounds__(256) void gemm_xw_kernel(
    const float* __restrict__ A, const float* __restrict__ Bw,
    const float* __restrict__ bih, const float* __restrict__ bhh,
    float* __restrict__ C)
{
    __shared__ float As[16][132];
    __shared__ float Bs[16][132];
    const int tid = threadIdx.x;
    const int bm0 = blockIdx.y * 128;
    const int bn0 = blockIdx.x * 128;
    const int tx = tid & 15, ty = tid >> 4;

    float acc[8][8];
#pragma unroll
    for (int i = 0; i < 8; ++i)
#pragma unroll
        for (int j = 0; j < 8; ++j) acc[i][j] = 0.f;

    for (int k0 = 0; k0 < IDIM; k0 += 16) {
#pragma unroll
        for (int l = 0; l < 2; ++l) {
            const int idx = tid + l * 256;
            const int row = idx >> 2, kq = (idx & 3) * 4;
            const float4 va = *reinterpret_cast<const float4*>(
                &A[(size_t)(bm0 + row) * IDIM + k0 + kq]);
            As[kq + 0][row] = va.x; As[kq + 1][row] = va.y;
            As[kq + 2][row] = va.z; As[kq + 3][row] = va.w;
            const float4 vb = *reinterpret_cast<const float4*>(
                &Bw[(size_t)(bn0 + row) * IDIM + k0 + kq]);
            Bs[kq + 0][row] = vb.x; Bs[kq + 1][row] = vb.y;
            Bs[kq + 2][row] = vb.z; Bs[kq + 3][row] = vb.w;
        }
        __syncthreads();
#pragma unroll
        for (int k = 0; k < 16; ++k) {
            const float4 alo = *reinterpret_cast<const float4*>(&As[k][4 * ty]);
            const float4 ahi = *reinterpret_cast<const float4*>(&As[k][64 + 4 * ty]);
            const float4 blo = *reinterpret_cast<const float4*>(&Bs[k][4 * tx]);
            const float4 bhi = *reinterpret_cast<const float4*>(&Bs[k][64 + 4 * tx]);
            const float a[8] = {alo.x, alo.y, alo.z, alo.w, ahi.x, ahi.y, ahi.z, ahi.w};
            const float b[8] = {blo.x, blo.y, blo.z, blo.w, bhi.x, bhi.y, bhi.z, bhi.w};
#pragma unroll
            for (int i = 0; i < 8; ++i)
#pragma unroll
                for (int j = 0; j < 8; ++j)
                    acc[i][j] = fmaf(a[i], b[j], acc[i][j]);
        }
        __syncthreads();
    }

    const float4 bl0 = *reinterpret_cast<const float4*>(&bih[bn0 + 4 * tx]);
    const float4 bl1 = *reinterpret_cast<const float4*>(&bhh[bn0 + 4 * tx]);
    const float4 bh0 = *reinterpret_cast<const float4*>(&bih[bn0 + 64 + 4 * tx]);
    const float4 bh1 = *reinterpret_cast<const float4*>(&bhh[bn0 + 64 + 4 * tx]);
    const float4 biaslo = {bl0.x + bl1.x, bl0.y + bl1.y, bl0.z + bl1.z, bl0.w + bl1.w};
    const float4 biashi = {bh0.x + bh1.x, bh0.y + bh1.y, bh0.z + bh1.z, bh0.w + bh1.w};
#pragma unroll
    for (int i = 0; i < 8; ++i) {
        const int m = bm0 + 4 * ty + (i & 3) + (i >> 2) * 64;
        const float4 lo = {acc[i][0] + biaslo.x, acc[i][1] + biaslo.y,
                           acc[i][2] + biaslo.z, acc[i][3] + biaslo.w};
        const float4 hi = {acc[i][4] + biashi.x, acc[i][5] + biashi.y,
                           acc[i][6] + biashi.z, acc[i][7] + biashi.w};
        *reinterpret_cast<float4*>(&C[(size_t)m * HDIM + bn0 + 4 * tx]) = lo;
        *reinterpret_cast<float4*>(&C[(size_t)m * HDIM + bn0 + 64 + 4 * tx]) = hi;
    }
}

// ================= Phase 2: persistent recurrence, flag barrier ===============
// 256 blocks x 256 threads. Block (bg,hg): rows bg*16..+15, cols hg*32..+31.
// W_hh slice [32][1024] persistent in LDS. hx exchange via sc0sc1 (MALL)
// accesses only -> no cache-wide fences; xw/W L2 lines survive all 256 steps.
// Barrier: distributed flags[bg*32+hg], 32-lane parallel poll.
__global__ __launch_bounds__(256, 1) void rnn_scan_kernel(
    const float* __restrict__ xw, const float* __restrict__ Whh,
    float* __restrict__ hx0buf, float* __restrict__ hx1buf,
    unsigned* __restrict__ flags)
{
    __shared__ f32x4 Ws4[32 * 256];      // 128 KB persistent W tile (swizzled)
    __shared__ f32x4 hs4[16 * 65];       // 16.6 KB hx chunk (padded rows)
    __shared__ float red[4][16][36];     // 9 KB cross-wave reduce scratch
    const int tid = threadIdx.x;
    const int bg  = blockIdx.x & 7;
    const int hg  = blockIdx.x >> 3;
    const int b0  = bg * 16;
    const int h0  = hg * 32;

    for (int idx = tid; idx < 32 * 256; idx += 256) {
        const int r = idx >> 8, q = idx & 255;
        Ws4[r * 256 + (q ^ (((r >> 3) & 3) << 2))] =
            *reinterpret_cast<const f32x4*>(&Whh[(size_t)(h0 + r) * HDIM + q * 4]);
    }

    const int ks    = tid >> 4;           // 0..15 k-split
    const int og    = tid & 15;
    const int bq    = og >> 2;
    const int hgrp  = og & 3;
    const int wv_sw = hgrp << 2;

    const int r0 = tid >> 6;              // 0..3 staging row base
    const int qq = tid & 63;              // f4 col within chunk

    const int out0 = tid * 2;
    const int ogo  = out0 >> 5;
    const int m0   = out0 & 31;
    const int b_ep = b0 + (ogo >> 2) * 4 + (m0 >> 3);
    const int h_ep = h0 + (ogo & 3) * 8 + (m0 & 7);

    unsigned* myflag = flags + (bg << 5) + hg;

    __syncthreads();                      // Ws ready

    for (int t = 0; t < T_STEPS; ++t) {
        const float* hcur = (t & 1) ? hx1buf : hx0buf;
        float*       hnxt = (t & 1) ? hx0buf : hx1buf;

        // ---- wait for all 32 blocks of this b-group to finish step t-1 ----
        if (t > 0) {
            if (tid < 64) {
                const unsigned want = (unsigned)t;
                const unsigned* fp = flags + (bg << 5) + (tid & 31);
                unsigned v;
                do {
                    v = (tid < 32)
                        ? __hip_atomic_load(fp, __ATOMIC_RELAXED,
                                            __HIP_MEMORY_SCOPE_AGENT)
                        : 0xFFFFFFFFu;
                } while (__any(v < want));
            }
            __syncthreads();
        }

        const float2 xv = *reinterpret_cast<const float2*>(
            &xw[((size_t)t * BATCH + b_ep) * HDIM + h_ep]);

        // ---- issue chunk-0 hx loads (coherent) ----
        f32x4 s0, s1, s2, s3;
        {
            const float* pb = hcur + (size_t)(b0 + r0) * HDIM + qq * 4;
            s0 = load_dev_x4(pb);
            s1 = load_dev_x4(pb + 4 * HDIM);
            s2 = load_dev_x4(pb + 8 * HDIM);
            s3 = load_dev_x4(pb + 12 * HDIM);
        }

        float acc[4][8];
#pragma unroll
        for (int i = 0; i < 4; ++i)
#pragma unroll
            for (int j = 0; j < 8; ++j) acc[i][j] = 0.f;

        for (int c = 0; c < 4; ++c) {
            wait_vm0();                   // chunk c data arrived
            hs4[(r0     ) * 65 + qq] = s0;
            hs4[(r0 +  4) * 65 + qq] = s1;
            hs4[(r0 +  8) * 65 + qq] = s2;
            hs4[(r0 + 12) * 65 + qq] = s3;
            if (c < 3) {                  // prefetch chunk c+1, hides under compute
                const float* pb = hcur + (size_t)(b0 + r0) * HDIM + (c + 1) * 256 + qq * 4;
                s0 = load_dev_x4(pb);
                s1 = load_dev_x4(pb + 4 * HDIM);
                s2 = load_dev_x4(pb + 8 * HDIM);
                s3 = load_dev_x4(pb + 12 * HDIM);
            }
            __syncthreads();
            const int cbase = c * 64;
#pragma unroll
            for (int kk = 0; kk < 4; ++kk) {
                const int qc = kk * 16 + ks;
                f32x4 hv[4];
#pragma unroll
                for (int i = 0; i < 4; ++i) hv[i] = hs4[(bq * 4 + i) * 65 + qc];
#pragma unroll
                for (int j = 0; j < 8; ++j) {
                    const f32x4 wv = Ws4[(hgrp * 8 + j) * 256 + ((cbase + qc) ^ wv_sw)];
#pragma unroll
                    for (int i = 0; i < 4; ++i)
                        acc[i][j] = fmaf(hv[i].x, wv.x, fmaf(hv[i].y, wv.y,
                                    fmaf(hv[i].z, wv.z, fmaf(hv[i].w, wv.w, acc[i][j]))));
                }
            }
            __syncthreads();
        }

        // ---- k-split reduce: shuffle over ks[1:0], LDS over ks[3:2] ----
#pragma unroll
        for (int i = 0; i < 4; ++i)
#pragma unroll
            for (int j = 0; j < 8; ++j) {
                float v = acc[i][j];
                v += __shfl_xor(v, 16, 64);
                v += __shfl_xor(v, 32, 64);
                acc[i][j] = v;
            }
        const int w = tid >> 6, lane = tid & 63;
        if (lane < 16) {
#pragma unroll
            for (int i = 0; i < 4; ++i)
#pragma unroll
                for (int j = 0; j < 8; ++j)
                    red[w][lane][i * 8 + j] = acc[i][j];
        }
        __syncthreads();

        const float y0 = red[0][ogo][m0]     + red[1][ogo][m0]
                       + red[2][ogo][m0]     + red[3][ogo][m0];
        const float y1 = red[0][ogo][m0 + 1] + red[1][ogo][m0 + 1]
                       + red[2][ogo][m0 + 1] + red[3][ogo][m0 + 1];
        f32x2 hnew;
        hnew.x = tanhf(xv.x + y0);
        hnew.y = tanhf(xv.y + y1);
        store_dev_x2(&hnxt[(size_t)b_ep * HDIM + h_ep], hnew);

        wait_vm0();                       // own stores acked at MALL
        __syncthreads();                  // => all threads' stores acked
        if (tid == 0) store_dev_u32(myflag, (unsigned)(t + 1));
    }
}

// ================= Phase 3: out = sigmoid(hx @ W_fc^T + b_fc) ==================
__global__ __launch_bounds__(64) void fc_kernel(
    const float* __restrict__ hx, const float* __restrict__ Wfc,
    const float* __restrict__ bfc, float* __restrict__ out)
{
    const int b = blockIdx.x >> 4, cls = blockIdx.x & 15, lane = threadIdx.x;
    float sum = 0.f;
#pragma unroll
    for (int qq = 0; qq < 4; ++qq) {
        const int f = (qq * 64 + lane) * 4;
        const float4 h4 = *reinterpret_cast<const float4*>(&hx[(size_t)b * HDIM + f]);
        const float4 w4 = *reinterpret_cast<const float4*>(&Wfc[(size_t)cls * HDIM + f]);
        sum = fmaf(h4.x, w4.x, fmaf(h4.y, w4.y, fmaf(h4.z, w4.z, fmaf(h4.w, w4.w, sum))));
    }
#pragma unroll
    for (int off = 32; off > 0; off >>= 1) sum += __shfl_xor(sum, off, 64);
    if (lane == 0) out[b * NCLS + cls] = 1.f / (1.f + expf(-(sum + bfc[cls])));
}

// ================================ launch ======================================
extern "C" void kernel_launch(void* const* d_in, const int* in_sizes, int n_in,
                              void* d_out, int out_size, void* d_ws, size_t ws_size,
                              hipStream_t stream) {
    const float* x   = (const float*)d_in[0];
    const float* Wih = (const float*)d_in[1];
    const float* Whh = (const float*)d_in[2];
    const float* bih = (const float*)d_in[3];
    const float* bhh = (const float*)d_in[4];
    const float* Wfc = (const float*)d_in[5];
    const float* bfc = (const float*)d_in[6];
    float* out = (float*)d_out;

    float* xw  = (float*)d_ws;
    float* hxA = xw + (size_t)T_STEPS * BATCH * HDIM;
    float* hxB = hxA + BATCH * HDIM;
    unsigned* flags = (unsigned*)(hxB + BATCH * HDIM);

    hipMemsetAsync(hxA, 0, BATCH * HDIM * sizeof(float), stream);
    hipMemsetAsync(flags, 0, 256 * sizeof(unsigned), stream);

    dim3 g1(HDIM / 128, (T_STEPS * BATCH) / 128);
    gemm_xw_kernel<<<g1, 256, 0, stream>>>(x, Wih, bih, bhh, xw);

    void* args[] = { (void*)&xw, (void*)&Whh, (void*)&hxA, (void*)&hxB, (void*)&flags };
    hipLaunchCooperativeKernel((const void*)rnn_scan_kernel, dim3(256), dim3(256),
                               args, 0, stream);

    fc_kernel<<<dim3(BATCH * NCLS), dim3(64), 0, stream>>>(hxA, Wfc, bfc, out);
}